// Round 1
// baseline (3316.633 us; speedup 1.0000x reference)
//
#include <hip/hip_runtime.h>
#include <math.h>

#define B_ 4
#define C_ 512
#define T_ 16
#define HW_ 784
#define CO_ 32
#define TT_ 48     // 3*T
#define T2_ 32     // 2*T
#define TEMP_ 4.0f

#define NCH 25      // ceil(784/32) key chunks of 32
#define PBLK 13     // ceil(784/64) query tiles of 64

typedef __attribute__((ext_vector_type(8))) short bf16x8;
typedef __attribute__((ext_vector_type(4))) float f32x4;

__device__ __forceinline__ ushort f2bf(float f) {
    union { float f; unsigned u; } v; v.f = f;
    unsigned r = v.u + 0x7fffu + ((v.u >> 16) & 1u);   // RNE
    return (ushort)(r >> 16);
}

// ---------------------------------------------------------------------------
// K1 "front": fused x->bf16 convert + Ws-projection (-> normalize -> xnorm,
// + center copy into out) + Wx-projection (-> xa). One pass over x.
//
// Block = 128 threads = 2 waves; block owns 64 positions (one per lane).
// Wave 0 accumulates channels [0,256), wave 1 [256,512); partials combined
// via 16 KB LDS. W reads use wave-uniform addresses (kernel arg + loop
// counter only) -> scalar s_load broadcasts, no LDS staging, no per-lane W
// traffic. grid: 784 blocks * 64 = 50176 = B*T*HW positions.
// ---------------------------------------------------------------------------
__global__ __launch_bounds__(128) void front_kernel(
    const float* __restrict__ x, const float* __restrict__ Ws,
    const float* __restrict__ Wx, float* __restrict__ out,
    ushort* __restrict__ xnorm, float* __restrict__ xa,
    ushort* __restrict__ xbf)
{
    __shared__ float accl[64][64];   // [oidx 0..63][lane] partials, 16 KB

    const int tid   = threadIdx.x;
    const int chalf = tid >> 6;      // which c-half this wave owns
    const int lane  = tid & 63;

    const int pidx = blockIdx.x * 64 + lane;     // [0, 50176)
    const int b = pidx / (T_ * HW_);
    const int r = pidx % (T_ * HW_);
    const int t = r / HW_;
    const int p = r % HW_;

    const float* xp   = x   + ((size_t)(b * C_) * T_ + t) * HW_ + p;   // stride c: 12544
    ushort*      xbp  = xbf + ((size_t)(b * C_) * T_ + t) * HW_ + p;   // stride c: 12544
    float*       outc = out + ((size_t)b * C_ * TT_ + 3 * t + 1) * HW_ + p; // stride c: 37632

    const int c0 = chalf * 256;

    float as0[16], as1[16], ax0[16], ax1[16];
    #pragma unroll
    for (int i = 0; i < 16; ++i) { as0[i] = 0.f; as1[i] = 0.f; ax0[i] = 0.f; ax1[i] = 0.f; }

    for (int c = c0; c < c0 + 256; c += 4) {
        float xv[4];
        #pragma unroll
        for (int j = 0; j < 4; ++j) xv[j] = xp[(size_t)(c + j) * (T_ * HW_)];
        // center copy + bf16 convert (each wave covers its own c-range)
        #pragma unroll
        for (int j = 0; j < 4; ++j) outc[(size_t)(c + j) * (TT_ * HW_)] = xv[j];
        #pragma unroll
        for (int j = 0; j < 4; ++j) xbp[(size_t)(c + j) * (T_ * HW_)] = f2bf(xv[j]);

        // Ws rows 0..15  (uniform address -> s_load_dwordx4)
        #pragma unroll
        for (int o = 0; o < 16; ++o) {
            float4 wv = *reinterpret_cast<const float4*>(Ws + o * C_ + c);
            as0[o] += wv.x * xv[0] + wv.y * xv[1] + wv.z * xv[2] + wv.w * xv[3];
        }
        // Ws rows 16..31
        #pragma unroll
        for (int o = 0; o < 16; ++o) {
            float4 wv = *reinterpret_cast<const float4*>(Ws + (16 + o) * C_ + c);
            as1[o] += wv.x * xv[0] + wv.y * xv[1] + wv.z * xv[2] + wv.w * xv[3];
        }
        // Wx rows 0..15
        #pragma unroll
        for (int o = 0; o < 16; ++o) {
            float4 wv = *reinterpret_cast<const float4*>(Wx + o * C_ + c);
            ax0[o] += wv.x * xv[0] + wv.y * xv[1] + wv.z * xv[2] + wv.w * xv[3];
        }
        // Wx rows 16..31
        #pragma unroll
        for (int o = 0; o < 16; ++o) {
            float4 wv = *reinterpret_cast<const float4*>(Wx + (16 + o) * C_ + c);
            ax1[o] += wv.x * xv[0] + wv.y * xv[1] + wv.z * xv[2] + wv.w * xv[3];
        }
    }

    if (chalf == 1) {
        #pragma unroll
        for (int o = 0; o < 16; ++o) {
            accl[o][lane]      = as0[o];
            accl[16 + o][lane] = as1[o];
            accl[32 + o][lane] = ax0[o];
            accl[48 + o][lane] = ax1[o];
        }
    }
    __syncthreads();
    if (chalf == 0) {
        #pragma unroll
        for (int o = 0; o < 16; ++o) {
            as0[o] += accl[o][lane];
            as1[o] += accl[16 + o][lane];
            ax0[o] += accl[32 + o][lane];
            ax1[o] += accl[48 + o][lane];
        }
        // semantic -> L2 normalize -> bf16 xnorm
        float s = 0.f;
        #pragma unroll
        for (int o = 0; o < 16; ++o) s += as0[o] * as0[o] + as1[o] * as1[o];
        float sc = 1.f / fmaxf(sqrtf(s), 1e-12f);
        ushort tmp[CO_];
        #pragma unroll
        for (int o = 0; o < 16; ++o) {
            tmp[o]      = f2bf(as0[o] * sc);
            tmp[16 + o] = f2bf(as1[o] * sc);
        }
        uint4* dp = reinterpret_cast<uint4*>(xnorm + (size_t)pidx * CO_);
        #pragma unroll
        for (int j = 0; j < 4; ++j) dp[j] = reinterpret_cast<const uint4*>(tmp)[j];
        // raw projection -> xa fp32
        float fo[CO_];
        #pragma unroll
        for (int o = 0; o < 16; ++o) { fo[o] = ax0[o]; fo[16 + o] = ax1[o]; }
        float4* fp = reinterpret_cast<float4*>(xa + (size_t)pidx * CO_);
        #pragma unroll
        for (int j = 0; j < 8; ++j) fp[j] = reinterpret_cast<const float4*>(fo)[j];
    }
}

// ---------------------------------------------------------------------------
// K2: MFMA flash attention (two-pass, no accumulator rescale). UNCHANGED.
// ---------------------------------------------------------------------------
__global__ __launch_bounds__(256, 2) void attn_mfma(
    const ushort* __restrict__ xnorm, const ushort* __restrict__ xbf,
    float* __restrict__ out)
{
    __shared__ ushort Pbuf[2][64][40];   // P tiles, row stride 40 (80B = 20 banks)
    __shared__ float mrow_s[64], lrow_s[64];

    const int tid  = threadIdx.x;
    const int w    = tid >> 6;
    const int lane = tid & 63;
    const int l15  = lane & 15;
    const int quad = lane >> 4;

    const int blk   = blockIdx.x;
    const int pblk  = blk % PBLK;
    const int slice = blk / PBLK;
    const int n = slice & 1;
    const int t = (slice >> 1) & (T_ - 1);
    const int b = slice >> 5;
    const int tn = t + (n ? 1 : -1);
    const int tt = 3 * t + 2 * n;
    const int p0 = pblk * 64;

    float* outb = out + (size_t)b * C_ * TT_ * HW_ + (size_t)tt * HW_;

    if (tn < 0 || tn >= T_) {            // zero-padded boundary frame
        for (int i = tid; i < C_ * 16; i += 256) {
            int c = i >> 4, p = p0 + (i & 15) * 4;
            if (p < HW_) {
                float4 z = {0.f, 0.f, 0.f, 0.f};
                *reinterpret_cast<float4*>(outb + (size_t)c * (TT_ * HW_) + p) = z;
            }
        }
        return;
    }

    const ushort* qb = xnorm + (size_t)(b * T_ + t) * HW_ * CO_;
    const ushort* kb = xnorm + (size_t)(b * T_ + tn) * HW_ * CO_;
    const ushort* vb = xbf + ((size_t)b * C_ * T_ + tn) * HW_;

    // Q A-fragment for this wave's M-tile (constant across chunks & passes)
    const int qp = p0 + w * 16 + l15;
    const int qpc = qp < HW_ ? qp : HW_ - 1;
    const bf16x8 Aq = *reinterpret_cast<const bf16x8*>(qb + (size_t)qpc * CO_ + quad * 8);

    const f32x4 zf = {0.f, 0.f, 0.f, 0.f};

    // ---------------- pass A: row stats ----------------
    float m_run[4], l_run[4];
    #pragma unroll
    for (int r = 0; r < 4; ++r) { m_run[r] = -1e30f; l_run[r] = 0.f; }

    for (int ch = 0; ch < NCH; ++ch) {
        const int q0 = ch * 32;
        int k0 = q0 + l15;        int k0c = k0 < HW_ ? k0 : HW_ - 1;
        int k1 = q0 + 16 + l15;   int k1c = k1 < HW_ ? k1 : HW_ - 1;
        bf16x8 Bk0 = *reinterpret_cast<const bf16x8*>(kb + (size_t)k0c * CO_ + quad * 8);
        bf16x8 Bk1 = *reinterpret_cast<const bf16x8*>(kb + (size_t)k1c * CO_ + quad * 8);
        f32x4 S0 = __builtin_amdgcn_mfma_f32_16x16x32_bf16(Aq, Bk0, zf, 0, 0, 0);
        f32x4 S1 = __builtin_amdgcn_mfma_f32_16x16x32_bf16(Aq, Bk1, zf, 0, 0, 0);
        const bool v0 = k0 < HW_, v1 = k1 < HW_;
        #pragma unroll
        for (int r = 0; r < 4; ++r) {
            float s0 = v0 ? S0[r] * TEMP_ : -1e30f;
            float s1 = v1 ? S1[r] * TEMP_ : -1e30f;
            float mn = fmaxf(m_run[r], fmaxf(s0, s1));
            l_run[r] = l_run[r] * __expf(m_run[r] - mn) + __expf(s0 - mn) + __expf(s1 - mn);
            m_run[r] = mn;
        }
    }
    #pragma unroll
    for (int r = 0; r < 4; ++r) {
        float m_ = m_run[r], l_ = l_run[r];
        #pragma unroll
        for (int d = 1; d < 16; d <<= 1) {
            float mo = __shfl_xor(m_, d);
            float lo = __shfl_xor(l_, d);
            float mn = fmaxf(m_, mo);
            l_ = l_ * __expf(m_ - mn) + lo * __expf(mo - mn);
            m_ = mn;
        }
        if (l15 == 0) {
            int row = w * 16 + quad * 4 + r;
            mrow_s[row] = m_;
            lrow_s[row] = 1.f / l_;
        }
    }
    __syncthreads();

    float mrw[4], lirw[4];
    #pragma unroll
    for (int r = 0; r < 4; ++r) {
        mrw[r]  = mrow_s[w * 16 + quad * 4 + r];
        lirw[r] = lrow_s[w * 16 + quad * 4 + r];
    }

    // ---------------- pass B: P build + PV ----------------
    const int c0 = w * 128;
    f32x4 acc[4][8];
    #pragma unroll
    for (int mt = 0; mt < 4; ++mt)
        #pragma unroll
        for (int nt = 0; nt < 8; ++nt) acc[mt][nt] = zf;

    for (int ch = 0; ch < NCH; ++ch) {
        const int q0 = ch * 32;
        const int buf = ch & 1;
        {
            int k0 = q0 + l15;        int k0c = k0 < HW_ ? k0 : HW_ - 1;
            int k1 = q0 + 16 + l15;   int k1c = k1 < HW_ ? k1 : HW_ - 1;
            bf16x8 Bk0 = *reinterpret_cast<const bf16x8*>(kb + (size_t)k0c * CO_ + quad * 8);
            bf16x8 Bk1 = *reinterpret_cast<const bf16x8*>(kb + (size_t)k1c * CO_ + quad * 8);
            f32x4 S0 = __builtin_amdgcn_mfma_f32_16x16x32_bf16(Aq, Bk0, zf, 0, 0, 0);
            f32x4 S1 = __builtin_amdgcn_mfma_f32_16x16x32_bf16(Aq, Bk1, zf, 0, 0, 0);
            const bool v0 = k0 < HW_, v1 = k1 < HW_;
            #pragma unroll
            for (int r = 0; r < 4; ++r) {
                int row = w * 16 + quad * 4 + r;
                float p0v = v0 ? __expf(S0[r] * TEMP_ - mrw[r]) * lirw[r] : 0.f;
                float p1v = v1 ? __expf(S1[r] * TEMP_ - mrw[r]) * lirw[r] : 0.f;
                Pbuf[buf][row][l15]      = f2bf(p0v);
                Pbuf[buf][row][16 + l15] = f2bf(p1v);
            }
        }
        __syncthreads();

        // V B-fragments straight from global bf16 (lane: 8 contiguous keys)
        bf16x8 Bv[8];
        #pragma unroll
        for (int nt = 0; nt < 8; ++nt) {
            int c = c0 + nt * 16 + l15;
            Bv[nt] = *reinterpret_cast<const bf16x8*>(
                vb + (size_t)c * (T_ * HW_) + q0 + quad * 8);
        }
        #pragma unroll
        for (int mt = 0; mt < 4; ++mt) {
            bf16x8 Ap = *reinterpret_cast<const bf16x8*>(&Pbuf[buf][mt * 16 + l15][quad * 8]);
            #pragma unroll
            for (int nt = 0; nt < 8; ++nt)
                acc[mt][nt] = __builtin_amdgcn_mfma_f32_16x16x32_bf16(Ap, Bv[nt], acc[mt][nt], 0, 0, 0);
        }
        __syncthreads();
    }

    // epilogue: C-layout frag -> float4 stores (rows contiguous along reg)
    #pragma unroll
    for (int mt = 0; mt < 4; ++mt) {
        int pb = p0 + mt * 16;
        if (pb >= HW_) break;
        int prow = pb + quad * 4;
        #pragma unroll
        for (int nt = 0; nt < 8; ++nt) {
            int c = c0 + nt * 16 + l15;
            *reinterpret_cast<float4*>(outb + (size_t)c * (TT_ * HW_) + prow) =
                *reinterpret_cast<float4*>(&acc[mt][nt]);
        }
    }
}

// ---------------------------------------------------------------------------
// K3: gating, read-once. Block = 512 threads = 8 waves, owns 64 positions
// (one per lane). Wave w holds channels [w*64, w*64+64) of the out column in
// REGISTERS (fully unrolled, static indexing), accumulates its partial
// na[32], folds it into a scalar s_w = sum_o Watt[o]*xa[o]*na_w[o] (sigmoid
// arg is linear in wave partials), reduces s across waves via 2 KB LDS, then
// rescales from registers. W reads are wave-uniform -> s_load broadcasts.
// grid: 1568 * 64 = 100352 = B * 2T * HW. Boundary zeros stay zero.
// ---------------------------------------------------------------------------
__global__ __launch_bounds__(512) void gate_kernel(
    const float* __restrict__ Wn, const float* __restrict__ Watt,
    const float* __restrict__ xa, float* __restrict__ out)
{
    __shared__ float sl[8][64];   // per-wave sigmoid-arg partials

    const int tid  = threadIdx.x;
    const int w    = tid >> 6;
    const int lane = tid & 63;

    const int gid = blockIdx.x * 64 + lane;     // [0, 100352)
    const int b  = gid / (T2_ * HW_);
    const int r  = gid % (T2_ * HW_);
    const int t2 = r / HW_;
    const int p  = r % HW_;
    const int t = t2 >> 1, n = t2 & 1;
    const int tt = 3 * t + 2 * n;

    float* op = out + ((size_t)b * C_ * TT_ + tt) * HW_ + p;   // stride c: 37632
    const int cw = w * 64;

    float vals[64];
    float na[CO_];
    #pragma unroll
    for (int o = 0; o < CO_; ++o) na[o] = 0.f;

    #pragma unroll
    for (int j0 = 0; j0 < 64; j0 += 4) {
        #pragma unroll
        for (int j = 0; j < 4; ++j)
            vals[j0 + j] = op[(size_t)(cw + j0 + j) * (TT_ * HW_)];
        #pragma unroll
        for (int o = 0; o < 16; ++o) {
            float4 wv = *reinterpret_cast<const float4*>(Wn + o * C_ + cw + j0);
            na[o] += wv.x * vals[j0] + wv.y * vals[j0 + 1]
                   + wv.z * vals[j0 + 2] + wv.w * vals[j0 + 3];
        }
        #pragma unroll
        for (int o = 0; o < 16; ++o) {
            float4 wv = *reinterpret_cast<const float4*>(Wn + (16 + o) * C_ + cw + j0);
            na[16 + o] += wv.x * vals[j0] + wv.y * vals[j0 + 1]
                        + wv.z * vals[j0 + 2] + wv.w * vals[j0 + 3];
        }
    }

    // s_w = sum_o Watt[o] * xa[pos][o] * na_w[o]
    const float* xap = xa + ((size_t)(b * T_ + t) * HW_ + p) * CO_;
    float s = 0.f;
    #pragma unroll
    for (int o4 = 0; o4 < 8; ++o4) {
        float4 xv = *reinterpret_cast<const float4*>(xap + o4 * 4);
        float4 wa = *reinterpret_cast<const float4*>(Watt + o4 * 4);   // uniform
        s += wa.x * xv.x * na[o4 * 4 + 0] + wa.y * xv.y * na[o4 * 4 + 1]
           + wa.z * xv.z * na[o4 * 4 + 2] + wa.w * xv.w * na[o4 * 4 + 3];
    }
    sl[w][lane] = s;
    __syncthreads();

    float ssum = 0.f;
    #pragma unroll
    for (int i = 0; i < 8; ++i) ssum += sl[i][lane];
    float g = 1.f / (1.f + __expf(-ssum));

    #pragma unroll
    for (int j = 0; j < 64; ++j)
        op[(size_t)(cw + j) * (TT_ * HW_)] = vals[j] * g;
}

extern "C" void kernel_launch(void* const* d_in, const int* in_sizes, int n_in,
                              void* d_out, int out_size, void* d_ws, size_t ws_size,
                              hipStream_t stream) {
    const float* x    = (const float*)d_in[0];
    const float* Ws   = (const float*)d_in[1];
    const float* Wx   = (const float*)d_in[2];
    const float* Wn   = (const float*)d_in[3];
    const float* Watt = (const float*)d_in[4];
    float* out = (float*)d_out;

    // ws layout: xnorm bf16 (3,211,264 B) | xa fp32 (6,422,528 B) | x bf16 (51,380,224 B)
    ushort* xnorm = (ushort*)d_ws;
    float*  xa    = (float*)((char*)d_ws + 3211264);
    ushort* xbf   = (ushort*)((char*)d_ws + 3211264 + 6422528);

    front_kernel<<<dim3(784), dim3(128), 0, stream>>>(x, Ws, Wx, out, xnorm, xa, xbf);
    attn_mfma<<<dim3(128 * PBLK), dim3(256), 0, stream>>>(xnorm, xbf, out);
    gate_kernel<<<dim3(1568), dim3(512), 0, stream>>>(Wn, Watt, xa, out);
}

// Round 2
// 1070.433 us; speedup vs baseline: 3.0984x; 3.0984x over previous
//
#include <hip/hip_runtime.h>
#include <math.h>

#define B_ 4
#define C_ 512
#define T_ 16
#define HW_ 784
#define CO_ 32
#define TT_ 48     // 3*T
#define T2_ 32     // 2*T
#define TEMP_ 4.0f

#define NCH 25      // ceil(784/32) key chunks of 32
#define PBLK 13     // ceil(784/64) query tiles of 64

typedef __attribute__((ext_vector_type(8))) short bf16x8;
typedef __attribute__((ext_vector_type(4))) float f32x4;

__device__ __forceinline__ ushort f2bf(float f) {
    union { float f; unsigned u; } v; v.f = f;
    unsigned r = v.u + 0x7fffu + ((v.u >> 16) & 1u);   // RNE
    return (ushort)(r >> 16);
}

// ---------------------------------------------------------------------------
// K1 "front": fused x->bf16 convert + Ws-projection (-> normalize -> xnorm,
// + center copy into out) + Wx-projection (-> xa). One pass over x.
//
// Block = 256 threads = 4 waves; block owns 64 positions (lane = position).
// Wave w accumulates channels [w*128, w*128+128); partials combined via LDS,
// wave 0 finishes. W offsets are readfirstlane'd -> provably wave-uniform
// addresses -> s_load scalar broadcasts (no per-lane VMEM, no LDS staging).
// grid: 784 blocks * 64 = 50176 = B*T*HW positions. ~3 waves/SIMD.
// ---------------------------------------------------------------------------
__global__ __launch_bounds__(256) void front_kernel(
    const float* __restrict__ x, const float* __restrict__ Ws,
    const float* __restrict__ Wx, float* __restrict__ out,
    ushort* __restrict__ xnorm, float* __restrict__ xa,
    ushort* __restrict__ xbf)
{
    __shared__ float accl[3][64][64];   // waves 1..3 partials: [w-1][o][lane], 48 KB

    const int tid  = threadIdx.x;
    const int w    = tid >> 6;
    const int lane = tid & 63;

    const int pidx = blockIdx.x * 64 + lane;     // [0, 50176)
    const int b = pidx / (T_ * HW_);
    const int r = pidx % (T_ * HW_);
    const int t = r / HW_;
    const int p = r % HW_;

    const float* xp   = x   + ((size_t)(b * C_) * T_ + t) * HW_ + p;        // stride c: 12544
    ushort*      xbp  = xbf + ((size_t)(b * C_) * T_ + t) * HW_ + p;        // stride c: 12544
    float*       outc = out + ((size_t)b * C_ * TT_ + 3 * t + 1) * HW_ + p; // stride c: 37632

    const int c0 = __builtin_amdgcn_readfirstlane(w * 128);   // wave-uniform

    float as[32], ax[32];
    #pragma unroll
    for (int o = 0; o < 32; ++o) { as[o] = 0.f; ax[o] = 0.f; }

    for (int cc = 0; cc < 128; cc += 4) {
        const int c = c0 + cc;                   // uniform
        float xv[4];
        #pragma unroll
        for (int j = 0; j < 4; ++j) xv[j] = xp[(size_t)(c + j) * (T_ * HW_)];
        #pragma unroll
        for (int j = 0; j < 4; ++j) outc[(size_t)(c + j) * (TT_ * HW_)] = xv[j];
        #pragma unroll
        for (int j = 0; j < 4; ++j) xbp[(size_t)(c + j) * (T_ * HW_)] = f2bf(xv[j]);

        #pragma unroll
        for (int o = 0; o < 32; ++o) {
            float4 wv = *reinterpret_cast<const float4*>(Ws + o * C_ + c);  // s_load
            as[o] += wv.x * xv[0] + wv.y * xv[1] + wv.z * xv[2] + wv.w * xv[3];
        }
        #pragma unroll
        for (int o = 0; o < 32; ++o) {
            float4 wv = *reinterpret_cast<const float4*>(Wx + o * C_ + c);  // s_load
            ax[o] += wv.x * xv[0] + wv.y * xv[1] + wv.z * xv[2] + wv.w * xv[3];
        }
    }

    if (w != 0) {
        #pragma unroll
        for (int o = 0; o < 32; ++o) {
            accl[w - 1][o][lane]      = as[o];
            accl[w - 1][32 + o][lane] = ax[o];
        }
    }
    __syncthreads();
    if (w == 0) {
        #pragma unroll
        for (int o = 0; o < 32; ++o) {
            as[o] += accl[0][o][lane] + accl[1][o][lane] + accl[2][o][lane];
            ax[o] += accl[0][32 + o][lane] + accl[1][32 + o][lane] + accl[2][32 + o][lane];
        }
        // semantic -> L2 normalize -> bf16 xnorm
        float s = 0.f;
        #pragma unroll
        for (int o = 0; o < 32; ++o) s += as[o] * as[o];
        float sc = 1.f / fmaxf(sqrtf(s), 1e-12f);
        ushort tmp[CO_];
        #pragma unroll
        for (int o = 0; o < 32; ++o) tmp[o] = f2bf(as[o] * sc);
        uint4* dp = reinterpret_cast<uint4*>(xnorm + (size_t)pidx * CO_);
        #pragma unroll
        for (int j = 0; j < 4; ++j) dp[j] = reinterpret_cast<const uint4*>(tmp)[j];
        // raw projection -> xa fp32
        float4* fp = reinterpret_cast<float4*>(xa + (size_t)pidx * CO_);
        #pragma unroll
        for (int j = 0; j < 8; ++j) fp[j] = reinterpret_cast<const float4*>(ax)[j];
    }
}

// ---------------------------------------------------------------------------
// K2: MFMA flash attention (two-pass, no accumulator rescale). UNCHANGED.
// ---------------------------------------------------------------------------
__global__ __launch_bounds__(256, 2) void attn_mfma(
    const ushort* __restrict__ xnorm, const ushort* __restrict__ xbf,
    float* __restrict__ out)
{
    __shared__ ushort Pbuf[2][64][40];   // P tiles, row stride 40 (80B = 20 banks)
    __shared__ float mrow_s[64], lrow_s[64];

    const int tid  = threadIdx.x;
    const int w    = tid >> 6;
    const int lane = tid & 63;
    const int l15  = lane & 15;
    const int quad = lane >> 4;

    const int blk   = blockIdx.x;
    const int pblk  = blk % PBLK;
    const int slice = blk / PBLK;
    const int n = slice & 1;
    const int t = (slice >> 1) & (T_ - 1);
    const int b = slice >> 5;
    const int tn = t + (n ? 1 : -1);
    const int tt = 3 * t + 2 * n;
    const int p0 = pblk * 64;

    float* outb = out + (size_t)b * C_ * TT_ * HW_ + (size_t)tt * HW_;

    if (tn < 0 || tn >= T_) {            // zero-padded boundary frame
        for (int i = tid; i < C_ * 16; i += 256) {
            int c = i >> 4, p = p0 + (i & 15) * 4;
            if (p < HW_) {
                float4 z = {0.f, 0.f, 0.f, 0.f};
                *reinterpret_cast<float4*>(outb + (size_t)c * (TT_ * HW_) + p) = z;
            }
        }
        return;
    }

    const ushort* qb = xnorm + (size_t)(b * T_ + t) * HW_ * CO_;
    const ushort* kb = xnorm + (size_t)(b * T_ + tn) * HW_ * CO_;
    const ushort* vb = xbf + ((size_t)b * C_ * T_ + tn) * HW_;

    // Q A-fragment for this wave's M-tile (constant across chunks & passes)
    const int qp = p0 + w * 16 + l15;
    const int qpc = qp < HW_ ? qp : HW_ - 1;
    const bf16x8 Aq = *reinterpret_cast<const bf16x8*>(qb + (size_t)qpc * CO_ + quad * 8);

    const f32x4 zf = {0.f, 0.f, 0.f, 0.f};

    // ---------------- pass A: row stats ----------------
    float m_run[4], l_run[4];
    #pragma unroll
    for (int r = 0; r < 4; ++r) { m_run[r] = -1e30f; l_run[r] = 0.f; }

    for (int ch = 0; ch < NCH; ++ch) {
        const int q0 = ch * 32;
        int k0 = q0 + l15;        int k0c = k0 < HW_ ? k0 : HW_ - 1;
        int k1 = q0 + 16 + l15;   int k1c = k1 < HW_ ? k1 : HW_ - 1;
        bf16x8 Bk0 = *reinterpret_cast<const bf16x8*>(kb + (size_t)k0c * CO_ + quad * 8);
        bf16x8 Bk1 = *reinterpret_cast<const bf16x8*>(kb + (size_t)k1c * CO_ + quad * 8);
        f32x4 S0 = __builtin_amdgcn_mfma_f32_16x16x32_bf16(Aq, Bk0, zf, 0, 0, 0);
        f32x4 S1 = __builtin_amdgcn_mfma_f32_16x16x32_bf16(Aq, Bk1, zf, 0, 0, 0);
        const bool v0 = k0 < HW_, v1 = k1 < HW_;
        #pragma unroll
        for (int r = 0; r < 4; ++r) {
            float s0 = v0 ? S0[r] * TEMP_ : -1e30f;
            float s1 = v1 ? S1[r] * TEMP_ : -1e30f;
            float mn = fmaxf(m_run[r], fmaxf(s0, s1));
            l_run[r] = l_run[r] * __expf(m_run[r] - mn) + __expf(s0 - mn) + __expf(s1 - mn);
            m_run[r] = mn;
        }
    }
    #pragma unroll
    for (int r = 0; r < 4; ++r) {
        float m_ = m_run[r], l_ = l_run[r];
        #pragma unroll
        for (int d = 1; d < 16; d <<= 1) {
            float mo = __shfl_xor(m_, d);
            float lo = __shfl_xor(l_, d);
            float mn = fmaxf(m_, mo);
            l_ = l_ * __expf(m_ - mn) + lo * __expf(mo - mn);
            m_ = mn;
        }
        if (l15 == 0) {
            int row = w * 16 + quad * 4 + r;
            mrow_s[row] = m_;
            lrow_s[row] = 1.f / l_;
        }
    }
    __syncthreads();

    float mrw[4], lirw[4];
    #pragma unroll
    for (int r = 0; r < 4; ++r) {
        mrw[r]  = mrow_s[w * 16 + quad * 4 + r];
        lirw[r] = lrow_s[w * 16 + quad * 4 + r];
    }

    // ---------------- pass B: P build + PV ----------------
    const int c0 = w * 128;
    f32x4 acc[4][8];
    #pragma unroll
    for (int mt = 0; mt < 4; ++mt)
        #pragma unroll
        for (int nt = 0; nt < 8; ++nt) acc[mt][nt] = zf;

    for (int ch = 0; ch < NCH; ++ch) {
        const int q0 = ch * 32;
        const int buf = ch & 1;
        {
            int k0 = q0 + l15;        int k0c = k0 < HW_ ? k0 : HW_ - 1;
            int k1 = q0 + 16 + l15;   int k1c = k1 < HW_ ? k1 : HW_ - 1;
            bf16x8 Bk0 = *reinterpret_cast<const bf16x8*>(kb + (size_t)k0c * CO_ + quad * 8);
            bf16x8 Bk1 = *reinterpret_cast<const bf16x8*>(kb + (size_t)k1c * CO_ + quad * 8);
            f32x4 S0 = __builtin_amdgcn_mfma_f32_16x16x32_bf16(Aq, Bk0, zf, 0, 0, 0);
            f32x4 S1 = __builtin_amdgcn_mfma_f32_16x16x32_bf16(Aq, Bk1, zf, 0, 0, 0);
            const bool v0 = k0 < HW_, v1 = k1 < HW_;
            #pragma unroll
            for (int r = 0; r < 4; ++r) {
                int row = w * 16 + quad * 4 + r;
                float p0v = v0 ? __expf(S0[r] * TEMP_ - mrw[r]) * lirw[r] : 0.f;
                float p1v = v1 ? __expf(S1[r] * TEMP_ - mrw[r]) * lirw[r] : 0.f;
                Pbuf[buf][row][l15]      = f2bf(p0v);
                Pbuf[buf][row][16 + l15] = f2bf(p1v);
            }
        }
        __syncthreads();

        // V B-fragments straight from global bf16 (lane: 8 contiguous keys)
        bf16x8 Bv[8];
        #pragma unroll
        for (int nt = 0; nt < 8; ++nt) {
            int c = c0 + nt * 16 + l15;
            Bv[nt] = *reinterpret_cast<const bf16x8*>(
                vb + (size_t)c * (T_ * HW_) + q0 + quad * 8);
        }
        #pragma unroll
        for (int mt = 0; mt < 4; ++mt) {
            bf16x8 Ap = *reinterpret_cast<const bf16x8*>(&Pbuf[buf][mt * 16 + l15][quad * 8]);
            #pragma unroll
            for (int nt = 0; nt < 8; ++nt)
                acc[mt][nt] = __builtin_amdgcn_mfma_f32_16x16x32_bf16(Ap, Bv[nt], acc[mt][nt], 0, 0, 0);
        }
        __syncthreads();
    }

    // epilogue: C-layout frag -> float4 stores (rows contiguous along reg)
    #pragma unroll
    for (int mt = 0; mt < 4; ++mt) {
        int pb = p0 + mt * 16;
        if (pb >= HW_) break;
        int prow = pb + quad * 4;
        #pragma unroll
        for (int nt = 0; nt < 8; ++nt) {
            int c = c0 + nt * 16 + l15;
            *reinterpret_cast<float4*>(outb + (size_t)c * (TT_ * HW_) + prow) =
                *reinterpret_cast<float4*>(&acc[mt][nt]);
        }
    }
}

// ---------------------------------------------------------------------------
// K3: gating. Block = 256 threads = 4 waves, 64 positions (lane = position);
// wave w owns channels [w*128, w*128+128). Pass 1: read column slice,
// accumulate na[32] (registers only -- ~55 VGPR, no spill). Sigmoid arg is
// linear in per-wave partials -> scalar LDS reduce across 4 waves. Pass 2:
// re-read (block's own 128 KB, L2-hot) and scale. Wn offsets readfirstlane'd
// -> s_load broadcasts. grid: 1568 * 64 = 100352 = B*2T*HW. ~6 waves/SIMD.
// ---------------------------------------------------------------------------
__global__ __launch_bounds__(256) void gate_kernel(
    const float* __restrict__ Wn, const float* __restrict__ Watt,
    const float* __restrict__ xa, float* __restrict__ out)
{
    __shared__ float sl[4][64];   // per-wave sigmoid-arg partials

    const int tid  = threadIdx.x;
    const int w    = tid >> 6;
    const int lane = tid & 63;

    const int gid = blockIdx.x * 64 + lane;     // [0, 100352)
    const int b  = gid / (T2_ * HW_);
    const int r  = gid % (T2_ * HW_);
    const int t2 = r / HW_;
    const int p  = r % HW_;
    const int t = t2 >> 1, n = t2 & 1;
    const int tt = 3 * t + 2 * n;

    float* op = out + ((size_t)b * C_ * TT_ + tt) * HW_ + p;   // stride c: 37632
    const int cw = __builtin_amdgcn_readfirstlane(w * 128);    // wave-uniform

    float na[CO_];
    #pragma unroll
    for (int o = 0; o < CO_; ++o) na[o] = 0.f;

    for (int cc = 0; cc < 128; cc += 4) {
        const int c = cw + cc;                   // uniform
        float v0 = op[(size_t)(c + 0) * (TT_ * HW_)];
        float v1 = op[(size_t)(c + 1) * (TT_ * HW_)];
        float v2 = op[(size_t)(c + 2) * (TT_ * HW_)];
        float v3 = op[(size_t)(c + 3) * (TT_ * HW_)];
        #pragma unroll
        for (int o = 0; o < CO_; ++o) {
            float4 wv = *reinterpret_cast<const float4*>(Wn + o * C_ + c);  // s_load
            na[o] += wv.x * v0 + wv.y * v1 + wv.z * v2 + wv.w * v3;
        }
    }

    // s_w = sum_o Watt[o] * xa[pos][o] * na_w[o]  (sigmoid arg linear in waves)
    const float* xap = xa + ((size_t)(b * T_ + t) * HW_ + p) * CO_;
    float s = 0.f;
    #pragma unroll
    for (int o4 = 0; o4 < 8; ++o4) {
        float4 xv = *reinterpret_cast<const float4*>(xap + o4 * 4);
        float4 wa = *reinterpret_cast<const float4*>(Watt + o4 * 4);   // uniform
        s += wa.x * xv.x * na[o4 * 4 + 0] + wa.y * xv.y * na[o4 * 4 + 1]
           + wa.z * xv.z * na[o4 * 4 + 2] + wa.w * xv.w * na[o4 * 4 + 3];
    }
    sl[w][lane] = s;
    __syncthreads();

    float ssum = sl[0][lane] + sl[1][lane] + sl[2][lane] + sl[3][lane];
    float g = 1.f / (1.f + __expf(-ssum));

    for (int cc = 0; cc < 128; cc += 4) {
        const int c = cw + cc;
        float v0 = op[(size_t)(c + 0) * (TT_ * HW_)];
        float v1 = op[(size_t)(c + 1) * (TT_ * HW_)];
        float v2 = op[(size_t)(c + 2) * (TT_ * HW_)];
        float v3 = op[(size_t)(c + 3) * (TT_ * HW_)];
        op[(size_t)(c + 0) * (TT_ * HW_)] = v0 * g;
        op[(size_t)(c + 1) * (TT_ * HW_)] = v1 * g;
        op[(size_t)(c + 2) * (TT_ * HW_)] = v2 * g;
        op[(size_t)(c + 3) * (TT_ * HW_)] = v3 * g;
    }
}

extern "C" void kernel_launch(void* const* d_in, const int* in_sizes, int n_in,
                              void* d_out, int out_size, void* d_ws, size_t ws_size,
                              hipStream_t stream) {
    const float* x    = (const float*)d_in[0];
    const float* Ws   = (const float*)d_in[1];
    const float* Wx   = (const float*)d_in[2];
    const float* Wn   = (const float*)d_in[3];
    const float* Watt = (const float*)d_in[4];
    float* out = (float*)d_out;

    // ws layout: xnorm bf16 (3,211,264 B) | xa fp32 (6,422,528 B) | x bf16 (51,380,224 B)
    ushort* xnorm = (ushort*)d_ws;
    float*  xa    = (float*)((char*)d_ws + 3211264);
    ushort* xbf   = (ushort*)((char*)d_ws + 3211264 + 6422528);

    front_kernel<<<dim3(784), dim3(256), 0, stream>>>(x, Ws, Wx, out, xnorm, xa, xbf);
    attn_mfma<<<dim3(128 * PBLK), dim3(256), 0, stream>>>(xnorm, xbf, out);
    gate_kernel<<<dim3(1568), dim3(256), 0, stream>>>(Wn, Watt, xa, out);
}